// Round 1
// baseline (2175.881 us; speedup 1.0000x reference)
//
#include <hip/hip_runtime.h>
#include <hip/hip_bf16.h>

// 3-layer GCN: per layer  out = dinv .* scatter_add(dinv .* (X@W)) + b, relu
// dinv = rsqrt(deg), deg = 1 (self loop) + count of incoming edges (dst).

#define NNODES 100000

// ---------------- degree / dinv ----------------
__global__ __launch_bounds__(256) void deg_init_k(float* __restrict__ deg, int n) {
    int i = blockIdx.x * 256 + threadIdx.x;
    if (i < n) deg[i] = 1.0f;   // self loop
}

__global__ __launch_bounds__(256) void deg_edges_k(const int* __restrict__ dst,
                                                   float* __restrict__ deg, int e) {
    int i = blockIdx.x * 256 + threadIdx.x;
    if (i < e) atomicAdd(&deg[dst[i]], 1.0f);
}

__global__ __launch_bounds__(256) void deg_finish_k(float* __restrict__ deg, int n) {
    int i = blockIdx.x * 256 + threadIdx.x;
    if (i < n) deg[i] = rsqrtf(deg[i]);
}

// ---------------- GEMM: G = ACC = (X @ W) * dinv[row] ----------------
// block = 256 threads; tile BM x FOUT; each thread: 8 rows x 4 cols.
template<int FIN, int FOUT>
__global__ __launch_bounds__(256) void gemm_scale_k(
    const float* __restrict__ X, const float* __restrict__ W,
    const float* __restrict__ dinv,
    float* __restrict__ G, float* __restrict__ ACC, int n)
{
    constexpr int TC = FOUT / 4;      // thread-cols (32 or 16)
    constexpr int TR = 256 / TC;      // thread-rows (8 or 16)
    constexpr int BM = TR * 8;        // 64 or 128
    constexpr int BK = 32;
    constexpr int XP = BM + 4;        // pad: breaks bank conflicts, keeps 16B align

    __shared__ float xT[BK][XP];      // transposed X tile
    __shared__ float wS[BK][FOUT];

    const int tid = threadIdx.x;
    const int tx = tid % TC;
    const int ty = tid / TC;
    const int c0 = tx * 4;
    const int r0 = ty * 8;
    const int rowBase = blockIdx.x * BM;

    float acc[8][4] = {};

    for (int kk = 0; kk < FIN; kk += BK) {
        // stage X tile, transposed into LDS
        constexpr int XF4 = BM * BK / 4;
        for (int q = tid; q < XF4; q += 256) {
            int r  = q / (BK / 4);
            int k4 = (q % (BK / 4)) * 4;
            int gr = rowBase + r;
            if (gr > n - 1) gr = n - 1;                 // clamp (junk rows never stored)
            float4 v = *(const float4*)(X + (size_t)gr * FIN + kk + k4);
            xT[k4 + 0][r] = v.x; xT[k4 + 1][r] = v.y;
            xT[k4 + 2][r] = v.z; xT[k4 + 3][r] = v.w;
        }
        // stage W chunk
        constexpr int WF4 = BK * FOUT / 4;
        for (int q = tid; q < WF4; q += 256) {
            int r  = q / TC;
            int c4 = (q % TC) * 4;
            *(float4*)&wS[r][c4] = *(const float4*)(W + (size_t)(kk + r) * FOUT + c4);
        }
        __syncthreads();

        #pragma unroll
        for (int k = 0; k < BK; ++k) {
            float4 a0 = *(const float4*)&xT[k][r0];
            float4 a1 = *(const float4*)&xT[k][r0 + 4];
            float4 wv = *(const float4*)&wS[k][c0];
            float av[8] = {a0.x, a0.y, a0.z, a0.w, a1.x, a1.y, a1.z, a1.w};
            #pragma unroll
            for (int r = 0; r < 8; ++r) {
                acc[r][0] += av[r] * wv.x;
                acc[r][1] += av[r] * wv.y;
                acc[r][2] += av[r] * wv.z;
                acc[r][3] += av[r] * wv.w;
            }
        }
        __syncthreads();
    }

    #pragma unroll
    for (int r = 0; r < 8; ++r) {
        int gr = rowBase + r0 + r;
        if (gr < n) {
            float s = dinv[gr];
            float4 v = make_float4(acc[r][0] * s, acc[r][1] * s,
                                   acc[r][2] * s, acc[r][3] * s);
            *(float4*)(G   + (size_t)gr * FOUT + c0) = v;
            *(float4*)(ACC + (size_t)gr * FOUT + c0) = v;
        }
    }
}

// ---------------- scatter-add over edges ----------------
// thread = (edge, feature); fully coalesced gather + coalesced atomics.
template<int LOGF>
__global__ __launch_bounds__(256) void scatter_add_k(
    const int* __restrict__ src, const int* __restrict__ dst,
    const float* __restrict__ g, float* __restrict__ acc,
    unsigned long long total)
{
    unsigned long long gid = (unsigned long long)blockIdx.x * 256ull + threadIdx.x;
    if (gid >= total) return;
    unsigned e = (unsigned)(gid >> LOGF);
    unsigned f = (unsigned)(gid & ((1u << LOGF) - 1u));
    int s = src[e];
    int d = dst[e];
    atomicAdd(acc + (((size_t)d) << LOGF) + f, g[(((size_t)s) << LOGF) + f]);
}

// ---------------- epilogue: out = acc*dinv[row] + b (, relu) ----------------
template<int LOGF4, bool RELU>
__global__ __launch_bounds__(256) void epilogue_k(
    const float* __restrict__ acc, const float* __restrict__ dinv,
    const float* __restrict__ bias, float* __restrict__ out, int n)
{
    unsigned gid = blockIdx.x * 256u + threadIdx.x;   // over n * F/4
    unsigned i  = gid >> LOGF4;
    if (i >= (unsigned)n) return;
    unsigned f4 = gid & ((1u << LOGF4) - 1u);
    float s = dinv[i];
    float4 a = ((const float4*)acc)[gid];
    float4 b = ((const float4*)bias)[f4];
    float4 v = make_float4(fmaf(a.x, s, b.x), fmaf(a.y, s, b.y),
                           fmaf(a.z, s, b.z), fmaf(a.w, s, b.w));
    if (RELU) {
        v.x = fmaxf(v.x, 0.0f); v.y = fmaxf(v.y, 0.0f);
        v.z = fmaxf(v.z, 0.0f); v.w = fmaxf(v.w, 0.0f);
    }
    ((float4*)out)[gid] = v;
}

extern "C" void kernel_launch(void* const* d_in, const int* in_sizes, int n_in,
                              void* d_out, int out_size, void* d_ws, size_t ws_size,
                              hipStream_t stream) {
    const float* x  = (const float*)d_in[0];
    const int*   ei = (const int*)d_in[1];     // [2, E] int32
    const float* W1 = (const float*)d_in[2];
    const float* b1 = (const float*)d_in[3];
    const float* W2 = (const float*)d_in[4];
    const float* b2 = (const float*)d_in[5];
    const float* W3 = (const float*)d_in[6];
    const float* b3 = (const float*)d_in[7];
    float* out = (float*)d_out;

    const int N = NNODES;
    const int E = in_sizes[1] / 2;
    const int* srcI = ei;
    const int* dstI = ei + E;

    char* ws = (char*)d_ws;
    size_t off = ((size_t)N * 4 + 255) & ~(size_t)255;
    float* dinv = (float*)ws;
    float* A = (float*)(ws + off);                 // g buffer
    float* B = A + (size_t)N * 128;                // acc buffer
    float* C = B + (size_t)N * 128;                // next-layer input

    const int nb_n = (N + 255) / 256;
    const int nb_e = (E + 255) / 256;

    // dinv = rsqrt(1 + indeg)
    deg_init_k<<<nb_n, 256, 0, stream>>>(dinv, N);
    deg_edges_k<<<nb_e, 256, 0, stream>>>(dstI, dinv, E);
    deg_finish_k<<<nb_n, 256, 0, stream>>>(dinv, N);

    unsigned long long tot128 = (unsigned long long)E << 7;
    unsigned long long tot64  = (unsigned long long)E << 6;
    int sb128 = (int)((tot128 + 255) / 256);
    int sb64  = (int)((tot64  + 255) / 256);

    // ---- layer 1: FEAT=256 -> HID=128 ----
    gemm_scale_k<256, 128><<<(N + 63) / 64, 256, 0, stream>>>(x, W1, dinv, A, B, N);
    scatter_add_k<7><<<sb128, 256, 0, stream>>>(srcI, dstI, A, B, tot128);
    epilogue_k<5, true><<<(N * 32 + 255) / 256, 256, 0, stream>>>(B, dinv, b1, C, N);

    // ---- layer 2: HID=128 -> HID=128 ----
    gemm_scale_k<128, 128><<<(N + 63) / 64, 256, 0, stream>>>(C, W2, dinv, A, B, N);
    scatter_add_k<7><<<sb128, 256, 0, stream>>>(srcI, dstI, A, B, tot128);
    epilogue_k<5, true><<<(N * 32 + 255) / 256, 256, 0, stream>>>(B, dinv, b2, C, N);

    // ---- layer 3: HID=128 -> OUT=64 ----
    gemm_scale_k<128, 64><<<(N + 127) / 128, 256, 0, stream>>>(C, W3, dinv, A, out, N);
    scatter_add_k<6><<<sb64, 256, 0, stream>>>(srcI, dstI, A, out, tot64);
    epilogue_k<4, false><<<(N * 16 + 255) / 256, 256, 0, stream>>>(out, dinv, b3, out, N);
}

// Round 2
// 828.912 us; speedup vs baseline: 2.6250x; 2.6250x over previous
//
#include <hip/hip_runtime.h>
#include <hip/hip_bf16.h>

// 3-layer GCN: per layer  out = relu(dinv .* segsum(dinv .* (X@W)) + b)
// segsum over incoming edges (dst-indexed CSR, built per call) + self loop.
// CSR gather replaces atomics: acc written once, src rows gathered from LLC.

#define NNODES 100000
#define SCAN_CHUNK 1024   // elements per scan block (256 thr x 4)

// ---------------- small utility kernels ----------------
__global__ __launch_bounds__(256) void zero_int_k(int* __restrict__ p, int n) {
    int i = blockIdx.x * 256 + threadIdx.x;
    if (i < n) p[i] = 0;
}

__global__ __launch_bounds__(256) void count_k(const int* __restrict__ dst,
                                               int* __restrict__ counts, int e) {
    int i = blockIdx.x * 256 + threadIdx.x;
    if (i < e) atomicAdd(&counts[dst[i]], 1);
}

// block-local exclusive scan over chunks of 1024 counts
__global__ __launch_bounds__(256) void scan_local_k(const int* __restrict__ counts,
                                                    int* __restrict__ rowptr,
                                                    int* __restrict__ bsum, int n) {
    __shared__ int lds[256];
    int t = threadIdx.x;
    int base = blockIdx.x * SCAN_CHUNK + t * 4;
    int c[4];
    #pragma unroll
    for (int q = 0; q < 4; ++q) c[q] = (base + q < n) ? counts[base + q] : 0;
    int tsum = c[0] + c[1] + c[2] + c[3];
    lds[t] = tsum;
    __syncthreads();
    // Hillis-Steele inclusive scan of thread sums
    #pragma unroll
    for (int off = 1; off < 256; off <<= 1) {
        int v = (t >= off) ? lds[t - off] : 0;
        __syncthreads();
        lds[t] += v;
        __syncthreads();
    }
    int excl = lds[t] - tsum;           // exclusive prefix of this thread
    if (t == 255) bsum[blockIdx.x] = lds[255];
    int run = excl;
    #pragma unroll
    for (int q = 0; q < 4; ++q) {
        if (base + q < n) rowptr[base + q] = run;
        run += c[q];
    }
}

// exclusive scan of block sums (tiny: <=128 entries) — single thread
__global__ __launch_bounds__(64) void scan_tops_k(int* __restrict__ bsum, int nb) {
    if (threadIdx.x == 0 && blockIdx.x == 0) {
        int run = 0;
        for (int b = 0; b < nb; ++b) {
            int v = bsum[b];
            bsum[b] = run;
            run += v;
        }
    }
}

// add block offsets; init cursor; dinv = rsqrt(1+indeg); rowptr[n] = E
__global__ __launch_bounds__(256) void scan_finish_k(
    const int* __restrict__ counts, int* __restrict__ rowptr,
    const int* __restrict__ bsum, int* __restrict__ cursor,
    float* __restrict__ dinv, int n, int e) {
    int i = blockIdx.x * 256 + threadIdx.x;
    if (i < n) {
        int v = rowptr[i] + bsum[i / SCAN_CHUNK];
        rowptr[i] = v;
        cursor[i] = v;
        dinv[i] = rsqrtf(1.0f + (float)counts[i]);
        if (i == 0) rowptr[n] = e;
    }
}

__global__ __launch_bounds__(256) void fill_k(const int* __restrict__ src,
                                              const int* __restrict__ dst,
                                              int* __restrict__ cursor,
                                              int* __restrict__ eidx, int e) {
    int i = blockIdx.x * 256 + threadIdx.x;
    if (i < e) {
        int p = atomicAdd(&cursor[dst[i]], 1);
        eidx[p] = src[i];
    }
}

// ---------------- GEMM: G = (X @ W) * dinv[row] ----------------
template<int FIN, int FOUT>
__global__ __launch_bounds__(256) void gemm_scale_k(
    const float* __restrict__ X, const float* __restrict__ W,
    const float* __restrict__ dinv, float* __restrict__ G, int n)
{
    constexpr int TC = FOUT / 4;      // thread-cols (32 or 16)
    constexpr int TR = 256 / TC;      // thread-rows (8 or 16)
    constexpr int BM = TR * 8;        // 64 or 128
    constexpr int BK = 32;
    constexpr int XP = BM + 4;

    __shared__ float xT[BK][XP];      // transposed X tile
    __shared__ float wS[BK][FOUT];

    const int tid = threadIdx.x;
    const int tx = tid % TC;
    const int ty = tid / TC;
    const int c0 = tx * 4;
    const int r0 = ty * 8;
    const int rowBase = blockIdx.x * BM;

    float acc[8][4] = {};

    for (int kk = 0; kk < FIN; kk += BK) {
        constexpr int XF4 = BM * BK / 4;
        for (int q = tid; q < XF4; q += 256) {
            int r  = q / (BK / 4);
            int k4 = (q % (BK / 4)) * 4;
            int gr = rowBase + r;
            if (gr > n - 1) gr = n - 1;
            float4 v = *(const float4*)(X + (size_t)gr * FIN + kk + k4);
            xT[k4 + 0][r] = v.x; xT[k4 + 1][r] = v.y;
            xT[k4 + 2][r] = v.z; xT[k4 + 3][r] = v.w;
        }
        constexpr int WF4 = BK * FOUT / 4;
        for (int q = tid; q < WF4; q += 256) {
            int r  = q / TC;
            int c4 = (q % TC) * 4;
            *(float4*)&wS[r][c4] = *(const float4*)(W + (size_t)(kk + r) * FOUT + c4);
        }
        __syncthreads();

        #pragma unroll
        for (int k = 0; k < BK; ++k) {
            float4 a0 = *(const float4*)&xT[k][r0];
            float4 a1 = *(const float4*)&xT[k][r0 + 4];
            float4 wv = *(const float4*)&wS[k][c0];
            float av[8] = {a0.x, a0.y, a0.z, a0.w, a1.x, a1.y, a1.z, a1.w};
            #pragma unroll
            for (int r = 0; r < 8; ++r) {
                acc[r][0] += av[r] * wv.x;
                acc[r][1] += av[r] * wv.y;
                acc[r][2] += av[r] * wv.z;
                acc[r][3] += av[r] * wv.w;
            }
        }
        __syncthreads();
    }

    #pragma unroll
    for (int r = 0; r < 8; ++r) {
        int gr = rowBase + r0 + r;
        if (gr < n) {
            float s = dinv[gr];
            float4 v = make_float4(acc[r][0] * s, acc[r][1] * s,
                                   acc[r][2] * s, acc[r][3] * s);
            *(float4*)(G + (size_t)gr * FOUT + c0) = v;
        }
    }
}

// ---------------- CSR gather segment-sum, F=128, fused epilogue ----------------
// one wave per node; lane covers features {2*lane, 2*lane+1} as float2.
template<bool RELU>
__global__ __launch_bounds__(256) void gather128_k(
    const float* __restrict__ g, const int* __restrict__ rowptr,
    const int* __restrict__ eidx, const float* __restrict__ dinv,
    const float* __restrict__ bias, float* __restrict__ out, int n)
{
    int wave = threadIdx.x >> 6;
    int lane = threadIdx.x & 63;
    int node = blockIdx.x * 4 + wave;
    if (node >= n) return;

    int beg = rowptr[node];
    int end = rowptr[node + 1];

    const float2* g2 = (const float2*)g;
    float2 a = g2[(size_t)node * 64 + lane];      // self loop
    float2 b = {0.f, 0.f};

    for (int j0 = beg; j0 < end; j0 += 64) {
        int id = (j0 + lane < end) ? eidx[j0 + lane] : 0;
        int m = end - j0; if (m > 64) m = 64;
        int t = 0;
        for (; t + 1 < m; t += 2) {
            int s0 = __shfl(id, t);
            int s1 = __shfl(id, t + 1);
            float2 v0 = g2[(size_t)s0 * 64 + lane];
            float2 v1 = g2[(size_t)s1 * 64 + lane];
            a.x += v0.x; a.y += v0.y;
            b.x += v1.x; b.y += v1.y;
        }
        if (t < m) {
            int s0 = __shfl(id, t);
            float2 v0 = g2[(size_t)s0 * 64 + lane];
            a.x += v0.x; a.y += v0.y;
        }
    }
    a.x += b.x; a.y += b.y;

    float sc = dinv[node];
    float2 bb = *(const float2*)(bias + 2 * lane);
    float ox = fmaf(a.x, sc, bb.x);
    float oy = fmaf(a.y, sc, bb.y);
    if (RELU) { ox = fmaxf(ox, 0.f); oy = fmaxf(oy, 0.f); }
    *(float2*)(out + (size_t)node * 128 + 2 * lane) = make_float2(ox, oy);
}

// F=64 variant: lane = feature (scalar float)
template<bool RELU>
__global__ __launch_bounds__(256) void gather64_k(
    const float* __restrict__ g, const int* __restrict__ rowptr,
    const int* __restrict__ eidx, const float* __restrict__ dinv,
    const float* __restrict__ bias, float* __restrict__ out, int n)
{
    int wave = threadIdx.x >> 6;
    int lane = threadIdx.x & 63;
    int node = blockIdx.x * 4 + wave;
    if (node >= n) return;

    int beg = rowptr[node];
    int end = rowptr[node + 1];

    float a = g[(size_t)node * 64 + lane];        // self loop
    float b = 0.f;

    for (int j0 = beg; j0 < end; j0 += 64) {
        int id = (j0 + lane < end) ? eidx[j0 + lane] : 0;
        int m = end - j0; if (m > 64) m = 64;
        int t = 0;
        for (; t + 1 < m; t += 2) {
            int s0 = __shfl(id, t);
            int s1 = __shfl(id, t + 1);
            a += g[(size_t)s0 * 64 + lane];
            b += g[(size_t)s1 * 64 + lane];
        }
        if (t < m) {
            int s0 = __shfl(id, t);
            a += g[(size_t)s0 * 64 + lane];
        }
    }
    a += b;

    float sc = dinv[node];
    float o = fmaf(a, sc, bias[lane]);
    if (RELU) o = fmaxf(o, 0.f);
    out[(size_t)node * 64 + lane] = o;
}

extern "C" void kernel_launch(void* const* d_in, const int* in_sizes, int n_in,
                              void* d_out, int out_size, void* d_ws, size_t ws_size,
                              hipStream_t stream) {
    const float* x  = (const float*)d_in[0];
    const int*   ei = (const int*)d_in[1];     // [2, E] int32
    const float* W1 = (const float*)d_in[2];
    const float* b1 = (const float*)d_in[3];
    const float* W2 = (const float*)d_in[4];
    const float* b2 = (const float*)d_in[5];
    const float* W3 = (const float*)d_in[6];
    const float* b3 = (const float*)d_in[7];
    float* out = (float*)d_out;

    const int N = NNODES;
    const int E = in_sizes[1] / 2;
    const int* srcI = ei;
    const int* dstI = ei + E;

    // workspace layout
    char* ws = (char*)d_ws;
    size_t p = 0;
    auto alloc = [&](size_t bytes) { void* r = ws + p; p = (p + bytes + 255) & ~(size_t)255; return r; };
    float* dinv   = (float*)alloc((size_t)N * 4);
    int*   counts = (int*)  alloc((size_t)N * 4);
    int*   rowptr = (int*)  alloc((size_t)(N + 1) * 4);
    int*   cursor = (int*)  alloc((size_t)N * 4);
    int*   bsum   = (int*)  alloc(1024);
    int*   eidx   = (int*)  alloc((size_t)E * 4);
    float* A      = (float*)alloc((size_t)N * 128 * 4);   // g buffer
    float* C      = (float*)alloc((size_t)N * 128 * 4);   // layer activations

    const int nb_n = (N + 255) / 256;
    const int nb_e = (E + 255) / 256;
    const int nb_scan = (N + SCAN_CHUNK - 1) / SCAN_CHUNK;   // 98
    const int nb_node4 = (N + 3) / 4;                        // 25000

    // ---- CSR build (dst-indexed) + dinv ----
    zero_int_k<<<nb_n, 256, 0, stream>>>(counts, N);
    count_k<<<nb_e, 256, 0, stream>>>(dstI, counts, E);
    scan_local_k<<<nb_scan, 256, 0, stream>>>(counts, rowptr, bsum, N);
    scan_tops_k<<<1, 64, 0, stream>>>(bsum, nb_scan);
    scan_finish_k<<<nb_n, 256, 0, stream>>>(counts, rowptr, bsum, cursor, dinv, N, E);
    fill_k<<<nb_e, 256, 0, stream>>>(srcI, dstI, cursor, eidx, E);

    // ---- layer 1: FEAT=256 -> HID=128 ----
    gemm_scale_k<256, 128><<<(N + 63) / 64, 256, 0, stream>>>(x, W1, dinv, A, N);
    gather128_k<true><<<nb_node4, 256, 0, stream>>>(A, rowptr, eidx, dinv, b1, C, N);

    // ---- layer 2: HID=128 -> HID=128 ----
    gemm_scale_k<128, 128><<<(N + 63) / 64, 256, 0, stream>>>(C, W2, dinv, A, N);
    gather128_k<true><<<nb_node4, 256, 0, stream>>>(A, rowptr, eidx, dinv, b2, C, N);

    // ---- layer 3: HID=128 -> OUT=64 ----
    gemm_scale_k<128, 64><<<(N + 127) / 128, 256, 0, stream>>>(C, W3, dinv, A, N);
    gather64_k<false><<<nb_node4, 256, 0, stream>>>(A, rowptr, eidx, dinv, b3, out, N);
}

// Round 3
// 629.464 us; speedup vs baseline: 3.4567x; 1.3169x over previous
//
#include <hip/hip_runtime.h>
#include <hip/hip_bf16.h>

// 3-layer GCN: per layer  out = relu(dinv .* segsum(dinv .* (X@W)) + b)
// fp16 message pipeline: GEMMs via mfma_f32_16x16x32_f16 (f32 accum),
// g / activations stored fp16 (halves gather traffic). CSR gather segsum.

#define NNODES 100000
#define SCAN_CHUNK 1024

typedef _Float16 half8  __attribute__((ext_vector_type(8)));
typedef _Float16 half2v __attribute__((ext_vector_type(2)));
typedef float    floatx4 __attribute__((ext_vector_type(4)));

// ---------------- small utility kernels ----------------
__global__ __launch_bounds__(256) void zero_int_k(int* __restrict__ p, int n) {
    int i = blockIdx.x * 256 + threadIdx.x;
    if (i < n) p[i] = 0;
}

__global__ __launch_bounds__(256) void count_k(const int* __restrict__ dst,
                                               int* __restrict__ counts, int e) {
    int i = blockIdx.x * 256 + threadIdx.x;
    if (i < e) atomicAdd(&counts[dst[i]], 1);
}

__global__ __launch_bounds__(256) void scan_local_k(const int* __restrict__ counts,
                                                    int* __restrict__ rowptr,
                                                    int* __restrict__ bsum, int n) {
    __shared__ int lds[256];
    int t = threadIdx.x;
    int base = blockIdx.x * SCAN_CHUNK + t * 4;
    int c[4];
    #pragma unroll
    for (int q = 0; q < 4; ++q) c[q] = (base + q < n) ? counts[base + q] : 0;
    int tsum = c[0] + c[1] + c[2] + c[3];
    lds[t] = tsum;
    __syncthreads();
    #pragma unroll
    for (int off = 1; off < 256; off <<= 1) {
        int v = (t >= off) ? lds[t - off] : 0;
        __syncthreads();
        lds[t] += v;
        __syncthreads();
    }
    int excl = lds[t] - tsum;
    if (t == 255) bsum[blockIdx.x] = lds[255];
    int run = excl;
    #pragma unroll
    for (int q = 0; q < 4; ++q) {
        if (base + q < n) rowptr[base + q] = run;
        run += c[q];
    }
}

__global__ __launch_bounds__(64) void scan_tops_k(int* __restrict__ bsum, int nb) {
    if (threadIdx.x == 0 && blockIdx.x == 0) {
        int run = 0;
        for (int b = 0; b < nb; ++b) { int v = bsum[b]; bsum[b] = run; run += v; }
    }
}

__global__ __launch_bounds__(256) void scan_finish_k(
    const int* __restrict__ counts, int* __restrict__ rowptr,
    const int* __restrict__ bsum, int* __restrict__ cursor,
    float* __restrict__ dinv, int n, int e) {
    int i = blockIdx.x * 256 + threadIdx.x;
    if (i < n) {
        int v = rowptr[i] + bsum[i / SCAN_CHUNK];
        rowptr[i] = v;
        cursor[i] = v;
        dinv[i] = rsqrtf(1.0f + (float)counts[i]);
        if (i == 0) rowptr[n] = e;
    }
}

__global__ __launch_bounds__(256) void fill_k(const int* __restrict__ src,
                                              const int* __restrict__ dst,
                                              int* __restrict__ cursor,
                                              int* __restrict__ eidx, int e) {
    int i = blockIdx.x * 256 + threadIdx.x;
    if (i < e) {
        int p = atomicAdd(&cursor[dst[i]], 1);
        eidx[p] = src[i];
    }
}

// ---------------- MFMA GEMM: G(fp16) = (X @ W) * dinv[row] ----------------
// block = 256 thr (4 waves); tile 128 rows x FOUT cols; wave = 32 rows.
// A frags straight from global; W staged transposed fp16 in LDS (K-chunked).
template<typename TA, int FIN, int FOUT>
__global__ __launch_bounds__(256) void gemm_mfma_k(
    const TA* __restrict__ X, const float* __restrict__ W,
    const float* __restrict__ dinv, _Float16* __restrict__ G, int n)
{
    constexpr int KC = (FIN > 128) ? 128 : FIN;
    constexpr int KP = KC + 8;           // pad: 2-way max bank alias on b-frag reads
    constexpr int NT = FOUT / 16;        // col tiles per wave
    __shared__ _Float16 wT[FOUT * KP];   // wT[n][k] = W[k][n]

    const int tid  = threadIdx.x;
    const int wave = tid >> 6;
    const int lane = tid & 63;
    const int mrow = lane & 15;          // A row / B col / D col within tile
    const int kq   = (lane >> 4) * 8;    // k-offset of this lane's 8 elements

    const int m0 = blockIdx.x * 128 + wave * 32;
    int r0 = m0 + mrow;      if (r0 > n - 1) r0 = n - 1;   // clamped junk rows
    int r1 = m0 + 16 + mrow; if (r1 > n - 1) r1 = n - 1;   // (never stored)

    floatx4 acc[2][NT];
    #pragma unroll
    for (int i = 0; i < 2; ++i)
        #pragma unroll
        for (int j = 0; j < NT; ++j) acc[i][j] = (floatx4){0.f, 0.f, 0.f, 0.f};

    for (int kc = 0; kc < FIN; kc += KC) {
        if (kc) __syncthreads();
        for (int q = tid; q < KC * FOUT; q += 256) {
            int k = q / FOUT, nn = q % FOUT;
            wT[nn * KP + k] = (_Float16)W[(size_t)(kc + k) * FOUT + nn];
        }
        __syncthreads();

        #pragma unroll
        for (int kk = 0; kk < KC; kk += 32) {
            half8 a0, a1;
            if constexpr (sizeof(TA) == 2) {
                const _Float16* xp = (const _Float16*)X;
                a0 = *(const half8*)(xp + (size_t)r0 * FIN + kc + kk + kq);
                a1 = *(const half8*)(xp + (size_t)r1 * FIN + kc + kk + kq);
            } else {
                const float* xp0 = (const float*)X + (size_t)r0 * FIN + kc + kk + kq;
                const float* xp1 = (const float*)X + (size_t)r1 * FIN + kc + kk + kq;
                float4 u0 = *(const float4*)xp0, u1 = *(const float4*)(xp0 + 4);
                float4 v0 = *(const float4*)xp1, v1 = *(const float4*)(xp1 + 4);
                a0 = (half8){(_Float16)u0.x, (_Float16)u0.y, (_Float16)u0.z, (_Float16)u0.w,
                             (_Float16)u1.x, (_Float16)u1.y, (_Float16)u1.z, (_Float16)u1.w};
                a1 = (half8){(_Float16)v0.x, (_Float16)v0.y, (_Float16)v0.z, (_Float16)v0.w,
                             (_Float16)v1.x, (_Float16)v1.y, (_Float16)v1.z, (_Float16)v1.w};
            }
            #pragma unroll
            for (int ct = 0; ct < NT; ++ct) {
                half8 b = *(const half8*)&wT[(ct * 16 + mrow) * KP + kk + kq];
                acc[0][ct] = __builtin_amdgcn_mfma_f32_16x16x32_f16(a0, b, acc[0][ct], 0, 0, 0);
                acc[1][ct] = __builtin_amdgcn_mfma_f32_16x16x32_f16(a1, b, acc[1][ct], 0, 0, 0);
            }
        }
    }

    // D layout: col = lane&15, row = (lane>>4)*4 + reg  [m89/m91 verified]
    #pragma unroll
    for (int rt = 0; rt < 2; ++rt) {
        #pragma unroll
        for (int reg = 0; reg < 4; ++reg) {
            int r = m0 + rt * 16 + (lane >> 4) * 4 + reg;
            if (r < n) {
                float s = dinv[r];
                #pragma unroll
                for (int ct = 0; ct < NT; ++ct) {
                    G[(size_t)r * FOUT + ct * 16 + mrow] = (_Float16)(acc[rt][ct][reg] * s);
                }
            }
        }
    }
}

// ---------------- CSR gather segment-sum, F=128, fused epilogue ----------------
// one wave per node; lane covers 2 features (fp16 pair = 4B load, coalesced).
template<bool RELU, typename OutT>
__global__ __launch_bounds__(256) void gather128_k(
    const _Float16* __restrict__ g, const int* __restrict__ rowptr,
    const int* __restrict__ eidx, const float* __restrict__ dinv,
    const float* __restrict__ bias, OutT* __restrict__ out, int n)
{
    int wave = threadIdx.x >> 6;
    int lane = threadIdx.x & 63;
    int node = blockIdx.x * 4 + wave;
    if (node >= n) return;

    int beg = rowptr[node];
    int end = rowptr[node + 1];

    const half2v* g2 = (const half2v*)g;
    half2v sv = g2[(size_t)node * 64 + lane];          // self loop
    float ax = (float)sv.x, ay = (float)sv.y;
    float bx = 0.f, by = 0.f;

    for (int j0 = beg; j0 < end; j0 += 64) {
        int id = (j0 + lane < end) ? eidx[j0 + lane] : 0;
        int m = end - j0; if (m > 64) m = 64;
        int t = 0;
        for (; t + 1 < m; t += 2) {
            int s0 = __shfl(id, t);
            int s1 = __shfl(id, t + 1);
            half2v v0 = g2[(size_t)s0 * 64 + lane];
            half2v v1 = g2[(size_t)s1 * 64 + lane];
            ax += (float)v0.x; ay += (float)v0.y;
            bx += (float)v1.x; by += (float)v1.y;
        }
        if (t < m) {
            int s0 = __shfl(id, t);
            half2v v0 = g2[(size_t)s0 * 64 + lane];
            ax += (float)v0.x; ay += (float)v0.y;
        }
    }
    ax += bx; ay += by;

    float sc = dinv[node];
    float2 bb = *(const float2*)(bias + 2 * lane);
    float ox = fmaf(ax, sc, bb.x);
    float oy = fmaf(ay, sc, bb.y);
    if (RELU) { ox = fmaxf(ox, 0.f); oy = fmaxf(oy, 0.f); }
    if constexpr (sizeof(OutT) == 2) {
        ((half2v*)out)[(size_t)node * 64 + lane] = (half2v){(_Float16)ox, (_Float16)oy};
    } else {
        ((float2*)out)[(size_t)node * 64 + lane] = make_float2(ox, oy);
    }
}

// F=64 variant: lane = feature, f32 output (final layer)
template<bool RELU>
__global__ __launch_bounds__(256) void gather64_k(
    const _Float16* __restrict__ g, const int* __restrict__ rowptr,
    const int* __restrict__ eidx, const float* __restrict__ dinv,
    const float* __restrict__ bias, float* __restrict__ out, int n)
{
    int wave = threadIdx.x >> 6;
    int lane = threadIdx.x & 63;
    int node = blockIdx.x * 4 + wave;
    if (node >= n) return;

    int beg = rowptr[node];
    int end = rowptr[node + 1];

    float a = (float)g[(size_t)node * 64 + lane];      // self loop
    float b = 0.f;

    for (int j0 = beg; j0 < end; j0 += 64) {
        int id = (j0 + lane < end) ? eidx[j0 + lane] : 0;
        int m = end - j0; if (m > 64) m = 64;
        int t = 0;
        for (; t + 1 < m; t += 2) {
            int s0 = __shfl(id, t);
            int s1 = __shfl(id, t + 1);
            a += (float)g[(size_t)s0 * 64 + lane];
            b += (float)g[(size_t)s1 * 64 + lane];
        }
        if (t < m) {
            int s0 = __shfl(id, t);
            a += (float)g[(size_t)s0 * 64 + lane];
        }
    }
    a += b;

    float sc = dinv[node];
    float o = fmaf(a, sc, bias[lane]);
    if (RELU) o = fmaxf(o, 0.f);
    out[(size_t)node * 64 + lane] = o;
}

extern "C" void kernel_launch(void* const* d_in, const int* in_sizes, int n_in,
                              void* d_out, int out_size, void* d_ws, size_t ws_size,
                              hipStream_t stream) {
    const float* x  = (const float*)d_in[0];
    const int*   ei = (const int*)d_in[1];     // [2, E] int32
    const float* W1 = (const float*)d_in[2];
    const float* b1 = (const float*)d_in[3];
    const float* W2 = (const float*)d_in[4];
    const float* b2 = (const float*)d_in[5];
    const float* W3 = (const float*)d_in[6];
    const float* b3 = (const float*)d_in[7];
    float* out = (float*)d_out;

    const int N = NNODES;
    const int E = in_sizes[1] / 2;
    const int* srcI = ei;
    const int* dstI = ei + E;

    // workspace layout
    char* ws = (char*)d_ws;
    size_t p = 0;
    auto alloc = [&](size_t bytes) { void* r = ws + p; p = (p + bytes + 255) & ~(size_t)255; return r; };
    float*     dinv   = (float*)    alloc((size_t)N * 4);
    int*       counts = (int*)      alloc((size_t)N * 4);
    int*       rowptr = (int*)      alloc((size_t)(N + 1) * 4);
    int*       cursor = (int*)      alloc((size_t)N * 4);
    int*       bsum   = (int*)      alloc(1024);
    int*       eidx   = (int*)      alloc((size_t)E * 4);
    _Float16*  A      = (_Float16*) alloc((size_t)N * 128 * 2);   // g buffer (fp16)
    _Float16*  Ch     = (_Float16*) alloc((size_t)N * 128 * 2);   // activations (fp16)

    const int nb_n = (N + 255) / 256;
    const int nb_e = (E + 255) / 256;
    const int nb_scan = (N + SCAN_CHUNK - 1) / SCAN_CHUNK;
    const int nb_node4 = (N + 3) / 4;
    const int nb_gemm = (N + 127) / 128;

    // ---- CSR build (dst-indexed) + dinv ----
    zero_int_k<<<nb_n, 256, 0, stream>>>(counts, N);
    count_k<<<nb_e, 256, 0, stream>>>(dstI, counts, E);
    scan_local_k<<<nb_scan, 256, 0, stream>>>(counts, rowptr, bsum, N);
    scan_tops_k<<<1, 64, 0, stream>>>(bsum, nb_scan);
    scan_finish_k<<<nb_n, 256, 0, stream>>>(counts, rowptr, bsum, cursor, dinv, N, E);
    fill_k<<<nb_e, 256, 0, stream>>>(srcI, dstI, cursor, eidx, E);

    // ---- layer 1: FEAT=256 -> HID=128 ----
    gemm_mfma_k<float, 256, 128><<<nb_gemm, 256, 0, stream>>>(x, W1, dinv, A, N);
    gather128_k<true, _Float16><<<nb_node4, 256, 0, stream>>>(A, rowptr, eidx, dinv, b1, Ch, N);

    // ---- layer 2: HID=128 -> HID=128 ----
    gemm_mfma_k<_Float16, 128, 128><<<nb_gemm, 256, 0, stream>>>(Ch, W2, dinv, A, N);
    gather128_k<true, _Float16><<<nb_node4, 256, 0, stream>>>(A, rowptr, eidx, dinv, b2, Ch, N);

    // ---- layer 3: HID=128 -> OUT=64 ----
    gemm_mfma_k<_Float16, 128, 64><<<nb_gemm, 256, 0, stream>>>(Ch, W3, dinv, A, N);
    gather64_k<false><<<nb_node4, 256, 0, stream>>>(A, rowptr, eidx, dinv, b3, out, N);
}

// Round 4
// 590.729 us; speedup vs baseline: 3.6834x; 1.0656x over previous
//
#include <hip/hip_runtime.h>
#include <hip/hip_bf16.h>

// 3-layer GCN: per layer  out = relu(dinv .* segsum(dinv .* (X@W)) + b)
// fp16 message pipeline: GEMMs via mfma_f32_16x16x32_f16 (f32 accum),
// g / activations stored fp16. CSR gather segsum (half-wave, 2 edges/load).
// CSR build atomics unrolled x8 for atomic-latency hiding.

#define NNODES 100000
#define SCAN_CHUNK 1024
#define EU 8   // edges per thread in count/fill

typedef _Float16 half8  __attribute__((ext_vector_type(8)));
typedef _Float16 half4v __attribute__((ext_vector_type(4)));
typedef _Float16 half2v __attribute__((ext_vector_type(2)));
typedef float    floatx4 __attribute__((ext_vector_type(4)));

// ---------------- small utility kernels ----------------
__global__ __launch_bounds__(256) void zero_int_k(int* __restrict__ p, int n) {
    int i = blockIdx.x * 256 + threadIdx.x;
    if (i < n) p[i] = 0;
}

// 8 edges per thread, contiguous (2x int4 loads), 8 independent atomics in flight
__global__ __launch_bounds__(256) void count_k(const int* __restrict__ dst,
                                               int* __restrict__ counts, int e) {
    int base = (blockIdx.x * 256 + threadIdx.x) * EU;
    if (base + EU <= e) {
        int4 d0 = *(const int4*)(dst + base);
        int4 d1 = *(const int4*)(dst + base + 4);
        atomicAdd(&counts[d0.x], 1); atomicAdd(&counts[d0.y], 1);
        atomicAdd(&counts[d0.z], 1); atomicAdd(&counts[d0.w], 1);
        atomicAdd(&counts[d1.x], 1); atomicAdd(&counts[d1.y], 1);
        atomicAdd(&counts[d1.z], 1); atomicAdd(&counts[d1.w], 1);
    } else {
        for (int i = base; i < e; ++i) atomicAdd(&counts[dst[i]], 1);
    }
}

__global__ __launch_bounds__(256) void scan_local_k(const int* __restrict__ counts,
                                                    int* __restrict__ rowptr,
                                                    int* __restrict__ bsum, int n) {
    __shared__ int lds[256];
    int t = threadIdx.x;
    int base = blockIdx.x * SCAN_CHUNK + t * 4;
    int c[4];
    #pragma unroll
    for (int q = 0; q < 4; ++q) c[q] = (base + q < n) ? counts[base + q] : 0;
    int tsum = c[0] + c[1] + c[2] + c[3];
    lds[t] = tsum;
    __syncthreads();
    #pragma unroll
    for (int off = 1; off < 256; off <<= 1) {
        int v = (t >= off) ? lds[t - off] : 0;
        __syncthreads();
        lds[t] += v;
        __syncthreads();
    }
    int excl = lds[t] - tsum;
    if (t == 255) bsum[blockIdx.x] = lds[255];
    int run = excl;
    #pragma unroll
    for (int q = 0; q < 4; ++q) {
        if (base + q < n) rowptr[base + q] = run;
        run += c[q];
    }
}

__global__ __launch_bounds__(64) void scan_tops_k(int* __restrict__ bsum, int nb) {
    if (threadIdx.x == 0 && blockIdx.x == 0) {
        int run = 0;
        for (int b = 0; b < nb; ++b) { int v = bsum[b]; bsum[b] = run; run += v; }
    }
}

__global__ __launch_bounds__(256) void scan_finish_k(
    const int* __restrict__ counts, int* __restrict__ rowptr,
    const int* __restrict__ bsum, int* __restrict__ cursor,
    float* __restrict__ dinv, int n, int e) {
    int i = blockIdx.x * 256 + threadIdx.x;
    if (i < n) {
        int v = rowptr[i] + bsum[i / SCAN_CHUNK];
        rowptr[i] = v;
        cursor[i] = v;
        dinv[i] = rsqrtf(1.0f + (float)counts[i]);
        if (i == 0) rowptr[n] = e;
    }
}

// 8 edges per thread; 8 independent cursor atomics issued back-to-back
__global__ __launch_bounds__(256) void fill_k(const int* __restrict__ src,
                                              const int* __restrict__ dst,
                                              int* __restrict__ cursor,
                                              int* __restrict__ eidx, int e) {
    int base = (blockIdx.x * 256 + threadIdx.x) * EU;
    if (base + EU <= e) {
        int4 d0 = *(const int4*)(dst + base);
        int4 d1 = *(const int4*)(dst + base + 4);
        int4 s0 = *(const int4*)(src + base);
        int4 s1 = *(const int4*)(src + base + 4);
        int p0 = atomicAdd(&cursor[d0.x], 1);
        int p1 = atomicAdd(&cursor[d0.y], 1);
        int p2 = atomicAdd(&cursor[d0.z], 1);
        int p3 = atomicAdd(&cursor[d0.w], 1);
        int p4 = atomicAdd(&cursor[d1.x], 1);
        int p5 = atomicAdd(&cursor[d1.y], 1);
        int p6 = atomicAdd(&cursor[d1.z], 1);
        int p7 = atomicAdd(&cursor[d1.w], 1);
        eidx[p0] = s0.x; eidx[p1] = s0.y; eidx[p2] = s0.z; eidx[p3] = s0.w;
        eidx[p4] = s1.x; eidx[p5] = s1.y; eidx[p6] = s1.z; eidx[p7] = s1.w;
    } else {
        for (int i = base; i < e; ++i) {
            int p = atomicAdd(&cursor[dst[i]], 1);
            eidx[p] = src[i];
        }
    }
}

// ---------------- MFMA GEMM: G(fp16) = (X @ W) * dinv[row] ----------------
template<typename TA, int FIN, int FOUT>
__global__ __launch_bounds__(256) void gemm_mfma_k(
    const TA* __restrict__ X, const float* __restrict__ W,
    const float* __restrict__ dinv, _Float16* __restrict__ G, int n)
{
    constexpr int KC = (FIN > 128) ? 128 : FIN;
    constexpr int KP = KC + 8;
    constexpr int NT = FOUT / 16;
    __shared__ _Float16 wT[FOUT * KP];   // wT[n][k] = W[k][n]

    const int tid  = threadIdx.x;
    const int wave = tid >> 6;
    const int lane = tid & 63;
    const int mrow = lane & 15;
    const int kq   = (lane >> 4) * 8;

    const int m0 = blockIdx.x * 128 + wave * 32;
    int r0 = m0 + mrow;      if (r0 > n - 1) r0 = n - 1;
    int r1 = m0 + 16 + mrow; if (r1 > n - 1) r1 = n - 1;

    floatx4 acc[2][NT];
    #pragma unroll
    for (int i = 0; i < 2; ++i)
        #pragma unroll
        for (int j = 0; j < NT; ++j) acc[i][j] = (floatx4){0.f, 0.f, 0.f, 0.f};

    for (int kc = 0; kc < FIN; kc += KC) {
        if (kc) __syncthreads();
        for (int q = tid; q < KC * FOUT; q += 256) {
            int k = q / FOUT, nn = q % FOUT;
            wT[nn * KP + k] = (_Float16)W[(size_t)(kc + k) * FOUT + nn];
        }
        __syncthreads();

        #pragma unroll
        for (int kk = 0; kk < KC; kk += 32) {
            half8 a0, a1;
            if constexpr (sizeof(TA) == 2) {
                const _Float16* xp = (const _Float16*)X;
                a0 = *(const half8*)(xp + (size_t)r0 * FIN + kc + kk + kq);
                a1 = *(const half8*)(xp + (size_t)r1 * FIN + kc + kk + kq);
            } else {
                const float* xp0 = (const float*)X + (size_t)r0 * FIN + kc + kk + kq;
                const float* xp1 = (const float*)X + (size_t)r1 * FIN + kc + kk + kq;
                float4 u0 = *(const float4*)xp0, u1 = *(const float4*)(xp0 + 4);
                float4 v0 = *(const float4*)xp1, v1 = *(const float4*)(xp1 + 4);
                a0 = (half8){(_Float16)u0.x, (_Float16)u0.y, (_Float16)u0.z, (_Float16)u0.w,
                             (_Float16)u1.x, (_Float16)u1.y, (_Float16)u1.z, (_Float16)u1.w};
                a1 = (half8){(_Float16)v0.x, (_Float16)v0.y, (_Float16)v0.z, (_Float16)v0.w,
                             (_Float16)v1.x, (_Float16)v1.y, (_Float16)v1.z, (_Float16)v1.w};
            }
            #pragma unroll
            for (int ct = 0; ct < NT; ++ct) {
                half8 b = *(const half8*)&wT[(ct * 16 + mrow) * KP + kk + kq];
                acc[0][ct] = __builtin_amdgcn_mfma_f32_16x16x32_f16(a0, b, acc[0][ct], 0, 0, 0);
                acc[1][ct] = __builtin_amdgcn_mfma_f32_16x16x32_f16(a1, b, acc[1][ct], 0, 0, 0);
            }
        }
    }

    #pragma unroll
    for (int rt = 0; rt < 2; ++rt) {
        #pragma unroll
        for (int reg = 0; reg < 4; ++reg) {
            int r = m0 + rt * 16 + (lane >> 4) * 4 + reg;
            if (r < n) {
                float s = dinv[r];
                #pragma unroll
                for (int ct = 0; ct < NT; ++ct) {
                    G[(size_t)r * FOUT + ct * 16 + mrow] = (_Float16)(acc[rt][ct][reg] * s);
                }
            }
        }
    }
}

// -------- CSR gather segsum, F=128: half-wave scheme, 2 edges per load --------
// wave = 1 node; lanes split into two 32-lane halves; each half covers the full
// 128-feature row via half4 (8B) loads; halves process different edges.
template<bool RELU, typename OutT>
__global__ __launch_bounds__(256) void gather128_k(
    const _Float16* __restrict__ g, const int* __restrict__ rowptr,
    const int* __restrict__ eidx, const float* __restrict__ dinv,
    const float* __restrict__ bias, OutT* __restrict__ out, int n)
{
    int wave = threadIdx.x >> 6;
    int lane = threadIdx.x & 63;
    int half = lane >> 5;
    int hl   = lane & 31;
    int node = blockIdx.x * 4 + wave;
    if (node >= n) return;

    int beg = rowptr[node];
    int end = rowptr[node + 1];

    const half4v* g4 = (const half4v*)g;     // row stride = 32 half4
    floatx4 aA = {0.f, 0.f, 0.f, 0.f}, aB = {0.f, 0.f, 0.f, 0.f};
    if (half == 0) {                          // self loop
        half4v v = g4[(size_t)node * 32 + hl];
        aA = (floatx4){(float)v.x, (float)v.y, (float)v.z, (float)v.w};
    }

    for (int j0 = beg; j0 < end; j0 += 64) {
        int m = end - j0; if (m > 64) m = 64;
        int id = (lane < m) ? eidx[j0 + lane] : 0;
        int t = 0;
        for (; t + 3 < m; t += 4) {
            int i0 = __shfl(id, t + half);
            int i1 = __shfl(id, t + 2 + half);
            half4v v0 = g4[(size_t)i0 * 32 + hl];
            half4v v1 = g4[(size_t)i1 * 32 + hl];
            aA.x += (float)v0.x; aA.y += (float)v0.y; aA.z += (float)v0.z; aA.w += (float)v0.w;
            aB.x += (float)v1.x; aB.y += (float)v1.y; aB.z += (float)v1.z; aB.w += (float)v1.w;
        }
        if (t + 1 < m) {
            int i0 = __shfl(id, t + half);
            half4v v0 = g4[(size_t)i0 * 32 + hl];
            aA.x += (float)v0.x; aA.y += (float)v0.y; aA.z += (float)v0.z; aA.w += (float)v0.w;
            t += 2;
        }
        if (t < m) {
            int i0 = __shfl(id, t);
            if (half == 0) {
                half4v v0 = g4[(size_t)i0 * 32 + hl];
                aA.x += (float)v0.x; aA.y += (float)v0.y; aA.z += (float)v0.z; aA.w += (float)v0.w;
            }
        }
    }
    aA.x += aB.x; aA.y += aB.y; aA.z += aB.z; aA.w += aB.w;
    // combine halves: lane<32 pulls lane+32's partial
    aA.x += __shfl_down(aA.x, 32);
    aA.y += __shfl_down(aA.y, 32);
    aA.z += __shfl_down(aA.z, 32);
    aA.w += __shfl_down(aA.w, 32);

    if (half == 0) {
        float sc = dinv[node];
        float4 bb = *(const float4*)(bias + 4 * hl);
        float o0 = fmaf(aA.x, sc, bb.x);
        float o1 = fmaf(aA.y, sc, bb.y);
        float o2 = fmaf(aA.z, sc, bb.z);
        float o3 = fmaf(aA.w, sc, bb.w);
        if (RELU) {
            o0 = fmaxf(o0, 0.f); o1 = fmaxf(o1, 0.f);
            o2 = fmaxf(o2, 0.f); o3 = fmaxf(o3, 0.f);
        }
        if constexpr (sizeof(OutT) == 2) {
            ((half4v*)out)[(size_t)node * 32 + hl] =
                (half4v){(_Float16)o0, (_Float16)o1, (_Float16)o2, (_Float16)o3};
        } else {
            *(float4*)((float*)out + (size_t)node * 128 + 4 * hl) =
                make_float4(o0, o1, o2, o3);
        }
    }
}

// -------- F=64 variant: half-wave, half2 (4B) loads, f32 output --------
template<bool RELU>
__global__ __launch_bounds__(256) void gather64_k(
    const _Float16* __restrict__ g, const int* __restrict__ rowptr,
    const int* __restrict__ eidx, const float* __restrict__ dinv,
    const float* __restrict__ bias, float* __restrict__ out, int n)
{
    int wave = threadIdx.x >> 6;
    int lane = threadIdx.x & 63;
    int half = lane >> 5;
    int hl   = lane & 31;
    int node = blockIdx.x * 4 + wave;
    if (node >= n) return;

    int beg = rowptr[node];
    int end = rowptr[node + 1];

    const half2v* g2 = (const half2v*)g;     // row stride = 32 half2
    float ax = 0.f, ay = 0.f, bx = 0.f, by = 0.f;
    if (half == 0) {
        half2v v = g2[(size_t)node * 32 + hl];
        ax = (float)v.x; ay = (float)v.y;
    }

    for (int j0 = beg; j0 < end; j0 += 64) {
        int m = end - j0; if (m > 64) m = 64;
        int id = (lane < m) ? eidx[j0 + lane] : 0;
        int t = 0;
        for (; t + 3 < m; t += 4) {
            int i0 = __shfl(id, t + half);
            int i1 = __shfl(id, t + 2 + half);
            half2v v0 = g2[(size_t)i0 * 32 + hl];
            half2v v1 = g2[(size_t)i1 * 32 + hl];
            ax += (float)v0.x; ay += (float)v0.y;
            bx += (float)v1.x; by += (float)v1.y;
        }
        if (t + 1 < m) {
            int i0 = __shfl(id, t + half);
            half2v v0 = g2[(size_t)i0 * 32 + hl];
            ax += (float)v0.x; ay += (float)v0.y;
            t += 2;
        }
        if (t < m) {
            int i0 = __shfl(id, t);
            if (half == 0) {
                half2v v0 = g2[(size_t)i0 * 32 + hl];
                ax += (float)v0.x; ay += (float)v0.y;
            }
        }
    }
    ax += bx; ay += by;
    ax += __shfl_down(ax, 32);
    ay += __shfl_down(ay, 32);

    if (half == 0) {
        float sc = dinv[node];
        float2 bb = *(const float2*)(bias + 2 * hl);
        float ox = fmaf(ax, sc, bb.x);
        float oy = fmaf(ay, sc, bb.y);
        if (RELU) { ox = fmaxf(ox, 0.f); oy = fmaxf(oy, 0.f); }
        *(float2*)(out + (size_t)node * 64 + 2 * hl) = make_float2(ox, oy);
    }
}

extern "C" void kernel_launch(void* const* d_in, const int* in_sizes, int n_in,
                              void* d_out, int out_size, void* d_ws, size_t ws_size,
                              hipStream_t stream) {
    const float* x  = (const float*)d_in[0];
    const int*   ei = (const int*)d_in[1];     // [2, E] int32
    const float* W1 = (const float*)d_in[2];
    const float* b1 = (const float*)d_in[3];
    const float* W2 = (const float*)d_in[4];
    const float* b2 = (const float*)d_in[5];
    const float* W3 = (const float*)d_in[6];
    const float* b3 = (const float*)d_in[7];
    float* out = (float*)d_out;

    const int N = NNODES;
    const int E = in_sizes[1] / 2;
    const int* srcI = ei;
    const int* dstI = ei + E;

    char* ws = (char*)d_ws;
    size_t p = 0;
    auto alloc = [&](size_t bytes) { void* r = ws + p; p = (p + bytes + 255) & ~(size_t)255; return r; };
    float*     dinv   = (float*)    alloc((size_t)N * 4);
    int*       counts = (int*)      alloc((size_t)N * 4);
    int*       rowptr = (int*)      alloc((size_t)(N + 1) * 4);
    int*       cursor = (int*)      alloc((size_t)N * 4);
    int*       bsum   = (int*)      alloc(1024);
    int*       eidx   = (int*)      alloc((size_t)E * 4);
    _Float16*  A      = (_Float16*) alloc((size_t)N * 128 * 2);
    _Float16*  Ch     = (_Float16*) alloc((size_t)N * 128 * 2);

    const int nb_n = (N + 255) / 256;
    const int nb_e8 = (E + 256 * EU - 1) / (256 * EU);
    const int nb_scan = (N + SCAN_CHUNK - 1) / SCAN_CHUNK;
    const int nb_node4 = (N + 3) / 4;
    const int nb_gemm = (N + 127) / 128;

    // ---- CSR build (dst-indexed) + dinv ----
    zero_int_k<<<nb_n, 256, 0, stream>>>(counts, N);
    count_k<<<nb_e8, 256, 0, stream>>>(dstI, counts, E);
    scan_local_k<<<nb_scan, 256, 0, stream>>>(counts, rowptr, bsum, N);
    scan_tops_k<<<1, 64, 0, stream>>>(bsum, nb_scan);
    scan_finish_k<<<nb_n, 256, 0, stream>>>(counts, rowptr, bsum, cursor, dinv, N, E);
    fill_k<<<nb_e8, 256, 0, stream>>>(srcI, dstI, cursor, eidx, E);

    // ---- layer 1: FEAT=256 -> HID=128 ----
    gemm_mfma_k<float, 256, 128><<<nb_gemm, 256, 0, stream>>>(x, W1, dinv, A, N);
    gather128_k<true, _Float16><<<nb_node4, 256, 0, stream>>>(A, rowptr, eidx, dinv, b1, Ch, N);

    // ---- layer 2: HID=128 -> HID=128 ----
    gemm_mfma_k<_Float16, 128, 128><<<nb_gemm, 256, 0, stream>>>(Ch, W2, dinv, A, N);
    gather128_k<true, _Float16><<<nb_node4, 256, 0, stream>>>(A, rowptr, eidx, dinv, b2, Ch, N);

    // ---- layer 3: HID=128 -> OUT=64 ----
    gemm_mfma_k<_Float16, 128, 64><<<nb_gemm, 256, 0, stream>>>(Ch, W3, dinv, A, N);
    gather64_k<false><<<nb_node4, 256, 0, stream>>>(A, rowptr, eidx, dinv, b3, out, N);
}